// Round 1
// baseline (366.511 us; speedup 1.0000x reference)
//
#include <hip/hip_runtime.h>
#include <stdint.h>

#define B_   16
#define S_   1024
#define N_   4096
#define C_   768
#define OUT_ 256

typedef short bf16x8 __attribute__((ext_vector_type(8)));
typedef float f32x4  __attribute__((ext_vector_type(4)));

#define GLOBAL_AS __attribute__((address_space(1)))
#define LDS_AS    __attribute__((address_space(3)))

__device__ __forceinline__ unsigned short f2bf(float f) {
    unsigned int u = __float_as_uint(f);
    u += 0x7fffu + ((u >> 16) & 1u);   // round-to-nearest-even
    return (unsigned short)(u >> 16);
}

__device__ __forceinline__ void gl_lds16(const void* gsrc, void* ldst) {
    __builtin_amdgcn_global_load_lds((const GLOBAL_AS void*)gsrc,
                                     (LDS_AS void*)ldst, 16, 0, 0);
}

// ---------------------------------------------------------------------------
// K0: W fp32 -> bf16 (256x768 = 196608 elements)
// ---------------------------------------------------------------------------
__global__ __launch_bounds__(256) void k_wconv(const float* __restrict__ W,
                                               unsigned short* __restrict__ Wb) {
    int i = blockIdx.x * 256 + threadIdx.x;
    Wb[i] = f2bf(W[i]);
}

// ---------------------------------------------------------------------------
// K1: argmin_n d2(s,n).  One wave per 4 seeds; lane scans n = k*64+lane.
// d2 replicated in the reference's fp32 op order: ((s2 - 2*dot) + p2),
// dot/p2/s2 as mul+add (no fma contraction). First-occurrence tie-break.
// ---------------------------------------------------------------------------
__global__ __launch_bounds__(256) void k_argmin(const float* __restrict__ seed,
                                                const float* __restrict__ pl,
                                                int* __restrict__ idx_out) {
    const int t    = threadIdx.x;
    const int lane = t & 63;
    const int w    = t >> 6;
    const int gw   = blockIdx.x * 4 + w;     // 4096 waves total
    const int b    = gw >> 8;                // 16 batches
    const int s0   = (gw & 255) * 4;         // 4 seeds per wave

    float sx[4], sy[4], sz[4], s2[4], best[4];
    int   bidx[4];
#pragma unroll
    for (int j = 0; j < 4; ++j) {
        const float* sp = seed + (size_t)(b * S_ + s0 + j) * 3;
        sx[j] = sp[0]; sy[j] = sp[1]; sz[j] = sp[2];
        s2[j] = __fadd_rn(__fadd_rn(__fmul_rn(sx[j], sx[j]),
                                    __fmul_rn(sy[j], sy[j])),
                          __fmul_rn(sz[j], sz[j]));
        best[j] = 3.4e38f;
        bidx[j] = 0;
    }
    const float* pb = pl + (size_t)b * N_ * 3;

    for (int k = 0; k < N_ / 64; ++k) {
        const int   n  = k * 64 + lane;
        const float px = pb[n * 3 + 0];
        const float py = pb[n * 3 + 1];
        const float pz = pb[n * 3 + 2];
        const float p2 = __fadd_rn(__fadd_rn(__fmul_rn(px, px),
                                             __fmul_rn(py, py)),
                                   __fmul_rn(pz, pz));
#pragma unroll
        for (int j = 0; j < 4; ++j) {
            float dot = __fadd_rn(__fadd_rn(__fmul_rn(sx[j], px),
                                            __fmul_rn(sy[j], py)),
                                  __fmul_rn(sz[j], pz));
            float d2  = __fadd_rn(__fsub_rn(s2[j], __fmul_rn(2.0f, dot)), p2);
            if (d2 < best[j]) { best[j] = d2; bidx[j] = n; }  // strict < keeps first n
        }
    }

#pragma unroll
    for (int j = 0; j < 4; ++j) {
#pragma unroll
        for (int off = 32; off >= 1; off >>= 1) {
            float ob = __shfl_xor(best[j], off, 64);
            int   oi = __shfl_xor(bidx[j], off, 64);
            bool take = (ob < best[j]) || (ob == best[j] && oi < bidx[j]);
            if (take) { best[j] = ob; bidx[j] = oi; }
        }
        if (lane == 0) idx_out[b * S_ + s0 + j] = bidx[j];
    }
}

// ---------------------------------------------------------------------------
// K2: gather + transpose + bf16-cast:  g_t[b][s][c] = bf16(f_last[b][c][idx[b][s]])
// Block = (b, c-tile of 24). One f_last row (16KB) active at a time ->
// L1-resident, every HBM line fetched exactly once. LDS tile [1024][26(pad)]
// (stride 26 shorts = 52B -> 13-bank lane stride, conflict-free column writes).
// ---------------------------------------------------------------------------
#define CT 24
__global__ __launch_bounds__(256) void k_gather(const float* __restrict__ f,
                                                const int* __restrict__ idx,
                                                unsigned short* __restrict__ gt) {
    __shared__ unsigned short tile[S_ * (CT + 2)];   // 1024*26 shorts = 52KB
    const int t  = threadIdx.x;
    const int b  = blockIdx.x >> 5;      // 512 blocks = 16 b x 32 c-tiles
    const int ct = blockIdx.x & 31;
    const int c0 = ct * CT;

    int idxv[4];
#pragma unroll
    for (int j = 0; j < 4; ++j) idxv[j] = idx[b * S_ + t + 256 * j];

    const float* fb = f + ((size_t)b * C_ + c0) * N_;
    for (int i = 0; i < CT; ++i) {
        const float* row = fb + (size_t)i * N_;
        float v0 = row[idxv[0]];
        float v1 = row[idxv[1]];
        float v2 = row[idxv[2]];
        float v3 = row[idxv[3]];
        tile[(t      ) * (CT + 2) + i] = f2bf(v0);
        tile[(t + 256) * (CT + 2) + i] = f2bf(v1);
        tile[(t + 512) * (CT + 2) + i] = f2bf(v2);
        tile[(t + 768) * (CT + 2) + i] = f2bf(v3);
    }
    __syncthreads();

    // write 1024 rows x 24 bf16 (48B) = 12288 dwords, coalesced-ish
    const size_t ob = (size_t)b * S_ * C_ + c0;      // element offset, row s=0
    for (int it = 0; it < 48; ++it) {
        int li = t + it * 256;
        int s  = li / 12;
        int cu = li - s * 12;
        unsigned int v = *(const unsigned int*)&tile[s * (CT + 2) + cu * 2];
        *(unsigned int*)(gt + ob + (size_t)s * C_ + cu * 2) = v;
    }
}

// ---------------------------------------------------------------------------
// K3: out[b][o][s] = sum_c Wb[o][c] * g_t[b][s][c] + bias[o]
// m97-style 128x128 tile, BK=32, mfma_f32_16x16x32_bf16, global_load_lds x16B.
// Grid = 16 b x 2 m-tiles x 8 n-tiles = 256 blocks, 256 thr (4 waves, 2x2).
// ---------------------------------------------------------------------------
__global__ __launch_bounds__(256) void k_gemm(const unsigned short* __restrict__ Wb,
                                              const unsigned short* __restrict__ gt,
                                              const float* __restrict__ bias,
                                              float* __restrict__ out) {
    __shared__ unsigned short ldsA[128 * 32];   // 8KB
    __shared__ unsigned short ldsB[128 * 32];   // 8KB
    const int t    = threadIdx.x;
    const int bid  = blockIdx.x;
    const int b    = bid >> 4;
    const int mt   = (bid >> 3) & 1;
    const int nt   = bid & 7;
    const int m0   = mt * 128;
    const int n0   = nt * 128;
    const int lane = t & 63;
    const int w    = t >> 6;
    const int wm   = w & 1, wn = w >> 1;
    const int quad = lane >> 4, l16 = lane & 15;

    f32x4 acc[4][4];
#pragma unroll
    for (int i = 0; i < 4; ++i)
#pragma unroll
        for (int j = 0; j < 4; ++j) acc[i][j] = (f32x4){0.f, 0.f, 0.f, 0.f};

    const int rowS = t >> 2;            // staging row 0..63 (t*8/32)
    const int kkS  = (t & 3) * 8;       // k element within 32
    const unsigned short* aSrc0 = Wb + (size_t)(m0 + rowS) * C_ + kkS;
    const unsigned short* aSrc1 = Wb + (size_t)(m0 + 64 + rowS) * C_ + kkS;
    const unsigned short* bBase = gt + (size_t)b * S_ * C_;
    const unsigned short* bSrc0 = bBase + (size_t)(n0 + rowS) * C_ + kkS;
    const unsigned short* bSrc1 = bBase + (size_t)(n0 + 64 + rowS) * C_ + kkS;
    unsigned short* la = ldsA + t * 8;  // byte offset t*16: wave-uniform + lane*16
    unsigned short* lb = ldsB + t * 8;

    for (int kt = 0; kt < C_ / 32; ++kt) {
        const int k0 = kt * 32;
        gl_lds16(aSrc0 + k0, la);
        gl_lds16(aSrc1 + k0, la + 2048);
        gl_lds16(bSrc0 + k0, lb);
        gl_lds16(bSrc1 + k0, lb + 2048);
        __syncthreads();   // compiler drains vmcnt before s_barrier

        bf16x8 aF[4], bF[4];
#pragma unroll
        for (int mi = 0; mi < 4; ++mi)
            aF[mi] = *(const bf16x8*)(ldsA + ((wm * 64 + mi * 16 + l16) * 32 + quad * 8));
#pragma unroll
        for (int ni = 0; ni < 4; ++ni)
            bF[ni] = *(const bf16x8*)(ldsB + ((wn * 64 + ni * 16 + l16) * 32 + quad * 8));
#pragma unroll
        for (int mi = 0; mi < 4; ++mi)
#pragma unroll
            for (int ni = 0; ni < 4; ++ni)
                acc[mi][ni] = __builtin_amdgcn_mfma_f32_16x16x32_bf16(
                    aF[mi], bF[ni], acc[mi][ni], 0, 0, 0);
        __syncthreads();
    }

    float* obase = out + (size_t)b * OUT_ * S_;
#pragma unroll
    for (int mi = 0; mi < 4; ++mi) {
#pragma unroll
        for (int r = 0; r < 4; ++r) {
            const int o  = m0 + wm * 64 + mi * 16 + quad * 4 + r;
            const float bo = bias[o];
            float* orow = obase + (size_t)o * S_;
#pragma unroll
            for (int ni = 0; ni < 4; ++ni) {
                const int s = n0 + wn * 64 + ni * 16 + l16;
                orow[s] = acc[mi][ni][r] + bo;
            }
        }
    }
}

// ---------------------------------------------------------------------------
// Workspace layout: [0,64K) idx int32[16][1024]
//                   [64K, 64K+384K) Wb bf16[256][768]
//                   [512K, 512K+24MB) g_t bf16[16][1024][768]
// total 25,690,112 bytes
// ---------------------------------------------------------------------------
extern "C" void kernel_launch(void* const* d_in, const int* in_sizes, int n_in,
                              void* d_out, int out_size, void* d_ws, size_t ws_size,
                              hipStream_t stream) {
    const float* seed = (const float*)d_in[0];   // [16,1024,3]
    const float* pl   = (const float*)d_in[1];   // [16,4096,3]
    const float* f    = (const float*)d_in[2];   // [16,768,4096]
    const float* W    = (const float*)d_in[3];   // [256,768]
    const float* bias = (const float*)d_in[4];   // [256]
    float* out = (float*)d_out;                  // [16,256,1024] fp32

    int* idx            = (int*)d_ws;
    unsigned short* Wb  = (unsigned short*)((char*)d_ws + 65536);
    unsigned short* gt  = (unsigned short*)((char*)d_ws + 524288);

    k_wconv <<<768,  256, 0, stream>>>(W, Wb);
    k_argmin<<<1024, 256, 0, stream>>>(seed, pl, idx);
    k_gather<<<512,  256, 0, stream>>>(f, idx, gt);
    k_gemm  <<<256,  256, 0, stream>>>(Wb, gt, bias, out);
}

// Round 2
// 359.080 us; speedup vs baseline: 1.0207x; 1.0207x over previous
//
#include <hip/hip_runtime.h>
#include <stdint.h>

#define B_   16
#define S_   1024
#define N_   4096
#define C_   768
#define OUT_ 256

typedef short bf16x8 __attribute__((ext_vector_type(8)));
typedef float f32x4  __attribute__((ext_vector_type(4)));

#define GLOBAL_AS __attribute__((address_space(1)))
#define LDS_AS    __attribute__((address_space(3)))

__device__ __forceinline__ unsigned short f2bf(float f) {
    unsigned int u = __float_as_uint(f);
    u += 0x7fffu + ((u >> 16) & 1u);   // round-to-nearest-even
    return (unsigned short)(u >> 16);
}

__device__ __forceinline__ void gl_lds16(const void* gsrc, void* ldst) {
    __builtin_amdgcn_global_load_lds((const GLOBAL_AS void*)gsrc,
                                     (LDS_AS void*)ldst, 16, 0, 0);
}

// ---------------------------------------------------------------------------
// K0: W fp32 -> bf16 (256x768 = 196608 elements)
// ---------------------------------------------------------------------------
__global__ __launch_bounds__(256) void k_wconv(const float* __restrict__ W,
                                               unsigned short* __restrict__ Wb) {
    int i = blockIdx.x * 256 + threadIdx.x;
    Wb[i] = f2bf(W[i]);
}

// ---------------------------------------------------------------------------
// K1: argmin_n d2(s,n).  One wave per 4 seeds; lane scans n = k*64+lane.
// d2 replicated in the reference's fp32 op order: ((s2 - 2*dot) + p2).
// First-occurrence tie-break (strict < scan + index-min on equal in reduce).
// ---------------------------------------------------------------------------
__global__ __launch_bounds__(256) void k_argmin(const float* __restrict__ seed,
                                                const float* __restrict__ pl,
                                                int* __restrict__ idx_out) {
    const int t    = threadIdx.x;
    const int lane = t & 63;
    const int w    = t >> 6;
    const int gw   = blockIdx.x * 4 + w;     // 4096 waves total
    const int b    = gw >> 8;                // 16 batches
    const int s0   = (gw & 255) * 4;         // 4 seeds per wave

    float sx[4], sy[4], sz[4], s2[4], best[4];
    int   bidx[4];
#pragma unroll
    for (int j = 0; j < 4; ++j) {
        const float* sp = seed + (size_t)(b * S_ + s0 + j) * 3;
        sx[j] = sp[0]; sy[j] = sp[1]; sz[j] = sp[2];
        s2[j] = __fadd_rn(__fadd_rn(__fmul_rn(sx[j], sx[j]),
                                    __fmul_rn(sy[j], sy[j])),
                          __fmul_rn(sz[j], sz[j]));
        best[j] = 3.4e38f;
        bidx[j] = 0;
    }
    const float* pb = pl + (size_t)b * N_ * 3;

    for (int k = 0; k < N_ / 64; ++k) {
        const int   n  = k * 64 + lane;
        const float px = pb[n * 3 + 0];
        const float py = pb[n * 3 + 1];
        const float pz = pb[n * 3 + 2];
        const float p2 = __fadd_rn(__fadd_rn(__fmul_rn(px, px),
                                             __fmul_rn(py, py)),
                                   __fmul_rn(pz, pz));
#pragma unroll
        for (int j = 0; j < 4; ++j) {
            float dot = __fadd_rn(__fadd_rn(__fmul_rn(sx[j], px),
                                            __fmul_rn(sy[j], py)),
                                  __fmul_rn(sz[j], pz));
            float d2  = __fadd_rn(__fsub_rn(s2[j], __fmul_rn(2.0f, dot)), p2);
            if (d2 < best[j]) { best[j] = d2; bidx[j] = n; }  // strict < keeps first n
        }
    }

#pragma unroll
    for (int j = 0; j < 4; ++j) {
#pragma unroll
        for (int off = 32; off >= 1; off >>= 1) {
            float ob = __shfl_xor(best[j], off, 64);
            int   oi = __shfl_xor(bidx[j], off, 64);
            bool take = (ob < best[j]) || (ob == best[j] && oi < bidx[j]);
            if (take) { best[j] = ob; bidx[j] = oi; }
        }
        if (lane == 0) idx_out[b * S_ + s0 + j] = bidx[j];
    }
}

// ---------------------------------------------------------------------------
// K2: gather + transpose + bf16-cast:  g_t[b][s][c] = bf16(f_last[b][c][idx[b][s]])
// ROUND 2 REWRITE: stream each 16KB f-row into LDS with coalesced
// global_load_lds (dwordx4), random-gather via ds_read_b32 (LDS scatter is
// ~10x cheaper than L1 scatter). Double-buffered rows: 32KB LDS -> 5 blk/CU.
// Block = (b, 8-c-row tile): 16*96 = 1536 blocks. Thread gathers 4 s-values
// per row into regs; epilogue: one 16B coalesced store per s.
// ---------------------------------------------------------------------------
#define CT 8
__global__ __launch_bounds__(256) void k_gather(const float* __restrict__ f,
                                                const int* __restrict__ idx,
                                                unsigned short* __restrict__ gt) {
    __shared__ float buf[2][N_];             // 2 x 16KB
    const int t  = threadIdx.x;
    const int b  = blockIdx.x / 96;
    const int ct = blockIdx.x % 96;
    const int c0 = ct * CT;

    int idxv[4];
#pragma unroll
    for (int j = 0; j < 4; ++j) idxv[j] = idx[b * S_ + t + 256 * j];

    const float* fb = f + ((size_t)b * C_ + c0) * N_;

    // prefetch row 0
#pragma unroll
    for (int k = 0; k < 4; ++k)
        gl_lds16(fb + t * 4 + k * 1024, &buf[0][t * 4 + k * 1024]);

    unsigned short og[4][CT] __attribute__((aligned(16)));

#pragma unroll
    for (int j = 0; j < CT; ++j) {
        __syncthreads();                     // drains vmcnt -> row j staged
        if (j + 1 < CT) {                    // prefetch row j+1 into other buf
            const float* row = fb + (size_t)(j + 1) * N_;
            float* dst = &buf[(j + 1) & 1][0];
#pragma unroll
            for (int k = 0; k < 4; ++k)
                gl_lds16(row + t * 4 + k * 1024, dst + t * 4 + k * 1024);
        }
        const float* src = &buf[j & 1][0];
#pragma unroll
        for (int si = 0; si < 4; ++si)
            og[si][j] = f2bf(src[idxv[si]]); // scattered ds_read_b32
        // buf[j&1] next overwritten by stage(j+2), which is issued only after
        // iteration j+1's __syncthreads -> all gathers of row j done. Safe.
    }

    const size_t ob = (size_t)b * S_ * C_ + c0;
#pragma unroll
    for (int si = 0; si < 4; ++si) {
        int s = t + si * 256;
        *(uint4*)(gt + ob + (size_t)s * C_) = *(const uint4*)og[si];
    }
}

// ---------------------------------------------------------------------------
// K3: out[b][o][s] = sum_c Wb[o][c] * g_t[b][s][c] + bias[o]
// m97-style 128x128 tile, BK=32, mfma_f32_16x16x32_bf16, global_load_lds x16B.
// ---------------------------------------------------------------------------
__global__ __launch_bounds__(256) void k_gemm(const unsigned short* __restrict__ Wb,
                                              const unsigned short* __restrict__ gt,
                                              const float* __restrict__ bias,
                                              float* __restrict__ out) {
    __shared__ unsigned short ldsA[128 * 32];   // 8KB
    __shared__ unsigned short ldsB[128 * 32];   // 8KB
    const int t    = threadIdx.x;
    const int bid  = blockIdx.x;
    const int b    = bid >> 4;
    const int mt   = (bid >> 3) & 1;
    const int nt   = bid & 7;
    const int m0   = mt * 128;
    const int n0   = nt * 128;
    const int lane = t & 63;
    const int w    = t >> 6;
    const int wm   = w & 1, wn = w >> 1;
    const int quad = lane >> 4, l16 = lane & 15;

    f32x4 acc[4][4];
#pragma unroll
    for (int i = 0; i < 4; ++i)
#pragma unroll
        for (int j = 0; j < 4; ++j) acc[i][j] = (f32x4){0.f, 0.f, 0.f, 0.f};

    const int rowS = t >> 2;            // staging row 0..63
    const int kkS  = (t & 3) * 8;       // k element within 32
    const unsigned short* aSrc0 = Wb + (size_t)(m0 + rowS) * C_ + kkS;
    const unsigned short* aSrc1 = Wb + (size_t)(m0 + 64 + rowS) * C_ + kkS;
    const unsigned short* bBase = gt + (size_t)b * S_ * C_;
    const unsigned short* bSrc0 = bBase + (size_t)(n0 + rowS) * C_ + kkS;
    const unsigned short* bSrc1 = bBase + (size_t)(n0 + 64 + rowS) * C_ + kkS;
    unsigned short* la = ldsA + t * 8;
    unsigned short* lb = ldsB + t * 8;

    for (int kt = 0; kt < C_ / 32; ++kt) {
        const int k0 = kt * 32;
        gl_lds16(aSrc0 + k0, la);
        gl_lds16(aSrc1 + k0, la + 2048);
        gl_lds16(bSrc0 + k0, lb);
        gl_lds16(bSrc1 + k0, lb + 2048);
        __syncthreads();

        bf16x8 aF[4], bF[4];
#pragma unroll
        for (int mi = 0; mi < 4; ++mi)
            aF[mi] = *(const bf16x8*)(ldsA + ((wm * 64 + mi * 16 + l16) * 32 + quad * 8));
#pragma unroll
        for (int ni = 0; ni < 4; ++ni)
            bF[ni] = *(const bf16x8*)(ldsB + ((wn * 64 + ni * 16 + l16) * 32 + quad * 8));
#pragma unroll
        for (int mi = 0; mi < 4; ++mi)
#pragma unroll
            for (int ni = 0; ni < 4; ++ni)
                acc[mi][ni] = __builtin_amdgcn_mfma_f32_16x16x32_bf16(
                    aF[mi], bF[ni], acc[mi][ni], 0, 0, 0);
        __syncthreads();
    }

    float* obase = out + (size_t)b * OUT_ * S_;
#pragma unroll
    for (int mi = 0; mi < 4; ++mi) {
#pragma unroll
        for (int r = 0; r < 4; ++r) {
            const int o  = m0 + wm * 64 + mi * 16 + quad * 4 + r;
            const float bo = bias[o];
            float* orow = obase + (size_t)o * S_;
#pragma unroll
            for (int ni = 0; ni < 4; ++ni) {
                const int s = n0 + wn * 64 + ni * 16 + l16;
                orow[s] = acc[mi][ni][r] + bo;
            }
        }
    }
}

// ---------------------------------------------------------------------------
// Workspace layout: [0,64K) idx int32[16][1024]
//                   [64K, 64K+384K) Wb bf16[256][768]
//                   [512K, 512K+24MB) g_t bf16[16][1024][768]
// ---------------------------------------------------------------------------
extern "C" void kernel_launch(void* const* d_in, const int* in_sizes, int n_in,
                              void* d_out, int out_size, void* d_ws, size_t ws_size,
                              hipStream_t stream) {
    const float* seed = (const float*)d_in[0];   // [16,1024,3]
    const float* pl   = (const float*)d_in[1];   // [16,4096,3]
    const float* f    = (const float*)d_in[2];   // [16,768,4096]
    const float* W    = (const float*)d_in[3];   // [256,768]
    const float* bias = (const float*)d_in[4];   // [256]
    float* out = (float*)d_out;                  // [16,256,1024] fp32

    int* idx            = (int*)d_ws;
    unsigned short* Wb  = (unsigned short*)((char*)d_ws + 65536);
    unsigned short* gt  = (unsigned short*)((char*)d_ws + 524288);

    k_wconv <<<768,  256, 0, stream>>>(W, Wb);
    k_argmin<<<1024, 256, 0, stream>>>(seed, pl, idx);
    k_gather<<<1536, 256, 0, stream>>>(f, idx, gt);
    k_gemm  <<<256,  256, 0, stream>>>(Wb, gt, bias, out);
}

// Round 3
// 356.352 us; speedup vs baseline: 1.0285x; 1.0077x over previous
//
#include <hip/hip_runtime.h>
#include <stdint.h>

#define B_   16
#define S_   1024
#define N_   4096
#define C_   768
#define OUT_ 256

typedef short bf16x8 __attribute__((ext_vector_type(8)));
typedef float f32x4  __attribute__((ext_vector_type(4)));

#define GLOBAL_AS __attribute__((address_space(1)))
#define LDS_AS    __attribute__((address_space(3)))

__device__ __forceinline__ unsigned short f2bf(float f) {
    unsigned int u = __float_as_uint(f);
    u += 0x7fffu + ((u >> 16) & 1u);   // round-to-nearest-even
    return (unsigned short)(u >> 16);
}

__device__ __forceinline__ void gl_lds16(const void* gsrc, void* ldst) {
    __builtin_amdgcn_global_load_lds((const GLOBAL_AS void*)gsrc,
                                     (LDS_AS void*)ldst, 16, 0, 0);
}

// ---------------------------------------------------------------------------
// K0: W fp32 -> bf16
// ---------------------------------------------------------------------------
__global__ __launch_bounds__(256) void k_wconv(const float* __restrict__ W,
                                               unsigned short* __restrict__ Wb) {
    int i = blockIdx.x * 256 + threadIdx.x;
    Wb[i] = f2bf(W[i]);
}

// ---------------------------------------------------------------------------
// K1: argmin_n d2(s,n).  Reference fp32 op order: ((s2 - 2*dot) + p2).
// ---------------------------------------------------------------------------
__global__ __launch_bounds__(256) void k_argmin(const float* __restrict__ seed,
                                                const float* __restrict__ pl,
                                                int* __restrict__ idx_out) {
    const int t    = threadIdx.x;
    const int lane = t & 63;
    const int w    = t >> 6;
    const int gw   = blockIdx.x * 4 + w;
    const int b    = gw >> 8;
    const int s0   = (gw & 255) * 4;

    float sx[4], sy[4], sz[4], s2[4], best[4];
    int   bidx[4];
#pragma unroll
    for (int j = 0; j < 4; ++j) {
        const float* sp = seed + (size_t)(b * S_ + s0 + j) * 3;
        sx[j] = sp[0]; sy[j] = sp[1]; sz[j] = sp[2];
        s2[j] = __fadd_rn(__fadd_rn(__fmul_rn(sx[j], sx[j]),
                                    __fmul_rn(sy[j], sy[j])),
                          __fmul_rn(sz[j], sz[j]));
        best[j] = 3.4e38f;
        bidx[j] = 0;
    }
    const float* pb = pl + (size_t)b * N_ * 3;

    for (int k = 0; k < N_ / 64; ++k) {
        const int   n  = k * 64 + lane;
        const float px = pb[n * 3 + 0];
        const float py = pb[n * 3 + 1];
        const float pz = pb[n * 3 + 2];
        const float p2 = __fadd_rn(__fadd_rn(__fmul_rn(px, px),
                                             __fmul_rn(py, py)),
                                   __fmul_rn(pz, pz));
#pragma unroll
        for (int j = 0; j < 4; ++j) {
            float dot = __fadd_rn(__fadd_rn(__fmul_rn(sx[j], px),
                                            __fmul_rn(sy[j], py)),
                                  __fmul_rn(sz[j], pz));
            float d2  = __fadd_rn(__fsub_rn(s2[j], __fmul_rn(2.0f, dot)), p2);
            if (d2 < best[j]) { best[j] = d2; bidx[j] = n; }
        }
    }

#pragma unroll
    for (int j = 0; j < 4; ++j) {
#pragma unroll
        for (int off = 32; off >= 1; off >>= 1) {
            float ob = __shfl_xor(best[j], off, 64);
            int   oi = __shfl_xor(bidx[j], off, 64);
            bool take = (ob < best[j]) || (ob == best[j] && oi < bidx[j]);
            if (take) { best[j] = ob; bidx[j] = oi; }
        }
        if (lane == 0) idx_out[b * S_ + s0 + j] = bidx[j];
    }
}

// ---------------------------------------------------------------------------
// K2 (ROUND 3): streaming transpose+cast: ft[b][n][c] = bf16(f[b][c][n]).
// 64c x 64n LDS tile, pad row to 72 shorts (144 B, keeps 16B alignment).
// Read: float4, fully coalesced. Write: 2x uint4 per thread, each output row
// gets exactly one full 128 B line per tile. NO scattered accesses anywhere.
// ---------------------------------------------------------------------------
__global__ __launch_bounds__(256) void k_transpose(const float* __restrict__ f,
                                                   unsigned short* __restrict__ ft) {
    __shared__ unsigned short tl[64][72];
    const int t  = threadIdx.x;
    const int nt = blockIdx.x & 63;
    const int ct = (blockIdx.x >> 6) % 12;
    const int b  = blockIdx.x / 768;
    const int c0 = ct * 64, n0 = nt * 64;

    const float* fb = f + ((size_t)b * C_ + c0) * N_ + n0;
#pragma unroll
    for (int r = 0; r < 4; ++r) {
        const int c  = (t >> 4) + 16 * r;
        const int nn = (t & 15) * 4;
        f32x4 v = *(const f32x4*)(fb + (size_t)c * N_ + nn);
#pragma unroll
        for (int i = 0; i < 4; ++i) tl[nn + i][c] = f2bf(v[i]);
    }
    __syncthreads();

    const int n  = t >> 2;
    const int c8 = (t & 3) * 16;
    uint4 o0 = *(const uint4*)&tl[n][c8];
    uint4 o1 = *(const uint4*)&tl[n][c8 + 8];
    unsigned short* od = ft + ((size_t)(b * N_ + n0 + n)) * C_ + c0 + c8;
    *(uint4*)(od)     = o0;
    *(uint4*)(od + 8) = o1;
}

// ---------------------------------------------------------------------------
// K3 (ROUND 3): fused row-gather GEMM.
// out[b][o][s] = sum_c Wb[o][c] * ft[b][idx[b][s]][c] + bias[o]
// B-tile rows are contiguous ft rows selected by idx; row pointers hoisted
// out of the K-loop. A-tile via global_load_lds (unchanged). B-fragment:
// 16B global load -> LDS write at the exact old DMA layout (ldsB + t*8).
// ---------------------------------------------------------------------------
__global__ __launch_bounds__(256) void k_gemm(const unsigned short* __restrict__ Wb,
                                              const unsigned short* __restrict__ ft,
                                              const int* __restrict__ idx,
                                              const float* __restrict__ bias,
                                              float* __restrict__ out) {
    __shared__ unsigned short ldsA[128 * 32];   // 8KB
    __shared__ unsigned short ldsB[128 * 32];   // 8KB
    const int t    = threadIdx.x;
    const int bid  = blockIdx.x;
    const int b    = bid >> 4;
    const int mt   = (bid >> 3) & 1;
    const int nt   = bid & 7;
    const int m0   = mt * 128;
    const int n0   = nt * 128;
    const int lane = t & 63;
    const int w    = t >> 6;
    const int wm   = w & 1, wn = w >> 1;
    const int quad = lane >> 4, l16 = lane & 15;

    f32x4 acc[4][4];
#pragma unroll
    for (int i = 0; i < 4; ++i)
#pragma unroll
        for (int j = 0; j < 4; ++j) acc[i][j] = (f32x4){0.f, 0.f, 0.f, 0.f};

    const int rowS = t >> 2;            // staging row 0..63
    const int kkS  = (t & 3) * 8;       // k element within 32
    const unsigned short* aSrc0 = Wb + (size_t)(m0 + rowS) * C_ + kkS;
    const unsigned short* aSrc1 = Wb + (size_t)(m0 + 64 + rowS) * C_ + kkS;

    const unsigned short* ftB = ft + (size_t)b * N_ * C_;
    const int nB0 = idx[b * S_ + n0 + rowS];
    const int nB1 = idx[b * S_ + n0 + 64 + rowS];
    const unsigned short* bSrc0 = ftB + (size_t)nB0 * C_ + kkS;
    const unsigned short* bSrc1 = ftB + (size_t)nB1 * C_ + kkS;

    unsigned short* la = ldsA + t * 8;  // t*8 shorts == rowS*32 + kkS

    for (int kt = 0; kt < C_ / 32; ++kt) {
        const int k0 = kt * 32;
        gl_lds16(aSrc0 + k0, la);
        gl_lds16(aSrc1 + k0, la + 2048);
        bf16x8 bv0 = *(const bf16x8*)(bSrc0 + k0);
        bf16x8 bv1 = *(const bf16x8*)(bSrc1 + k0);
        *(bf16x8*)(ldsB + t * 8)        = bv0;
        *(bf16x8*)(ldsB + 2048 + t * 8) = bv1;
        __syncthreads();

        bf16x8 aF[4], bF[4];
#pragma unroll
        for (int mi = 0; mi < 4; ++mi)
            aF[mi] = *(const bf16x8*)(ldsA + ((wm * 64 + mi * 16 + l16) * 32 + quad * 8));
#pragma unroll
        for (int ni = 0; ni < 4; ++ni)
            bF[ni] = *(const bf16x8*)(ldsB + ((wn * 64 + ni * 16 + l16) * 32 + quad * 8));
#pragma unroll
        for (int mi = 0; mi < 4; ++mi)
#pragma unroll
            for (int ni = 0; ni < 4; ++ni)
                acc[mi][ni] = __builtin_amdgcn_mfma_f32_16x16x32_bf16(
                    aF[mi], bF[ni], acc[mi][ni], 0, 0, 0);
        __syncthreads();
    }

    float* obase = out + (size_t)b * OUT_ * S_;
#pragma unroll
    for (int mi = 0; mi < 4; ++mi) {
#pragma unroll
        for (int r = 0; r < 4; ++r) {
            const int o  = m0 + wm * 64 + mi * 16 + quad * 4 + r;
            const float bo = bias[o];
            float* orow = obase + (size_t)o * S_;
#pragma unroll
            for (int ni = 0; ni < 4; ++ni) {
                const int s = n0 + wn * 64 + ni * 16 + l16;
                orow[s] = acc[mi][ni][r] + bo;
            }
        }
    }
}

// ---------------------------------------------------------------------------
// Workspace: [0,64K) idx int32[16][1024]
//            [64K,64K+384K) Wb bf16[256][768]
//            [512K, 512K+100.7MB) ft bf16[16][4096][768]
// ---------------------------------------------------------------------------
extern "C" void kernel_launch(void* const* d_in, const int* in_sizes, int n_in,
                              void* d_out, int out_size, void* d_ws, size_t ws_size,
                              hipStream_t stream) {
    const float* seed = (const float*)d_in[0];   // [16,1024,3]
    const float* pl   = (const float*)d_in[1];   // [16,4096,3]
    const float* f    = (const float*)d_in[2];   // [16,768,4096]
    const float* W    = (const float*)d_in[3];   // [256,768]
    const float* bias = (const float*)d_in[4];   // [256]
    float* out = (float*)d_out;                  // [16,256,1024] fp32

    int* idx            = (int*)d_ws;
    unsigned short* Wb  = (unsigned short*)((char*)d_ws + 65536);
    unsigned short* ft  = (unsigned short*)((char*)d_ws + 524288);

    k_wconv    <<<768,   256, 0, stream>>>(W, Wb);
    k_argmin   <<<1024,  256, 0, stream>>>(seed, pl, idx);
    k_transpose<<<12288, 256, 0, stream>>>(f, ft);
    k_gemm     <<<256,   256, 0, stream>>>(Wb, ft, idx, bias, out);
}

// Round 4
// 320.931 us; speedup vs baseline: 1.1420x; 1.1104x over previous
//
#include <hip/hip_runtime.h>
#include <stdint.h>

#define B_   16
#define S_   1024
#define N_   4096
#define C_   768
#define OUT_ 256

typedef short bf16x8 __attribute__((ext_vector_type(8)));
typedef short bf16x4 __attribute__((ext_vector_type(4)));
typedef float f32x4  __attribute__((ext_vector_type(4)));

#define GLOBAL_AS __attribute__((address_space(1)))
#define LDS_AS    __attribute__((address_space(3)))

__device__ __forceinline__ unsigned short f2bf(float f) {
    unsigned int u = __float_as_uint(f);
    u += 0x7fffu + ((u >> 16) & 1u);   // round-to-nearest-even
    return (unsigned short)(u >> 16);
}

__device__ __forceinline__ void gl_lds16(const void* gsrc, void* ldst) {
    __builtin_amdgcn_global_load_lds((const GLOBAL_AS void*)gsrc,
                                     (LDS_AS void*)ldst, 16, 0, 0);
}

// ---------------------------------------------------------------------------
// K0: W fp32 -> bf16
// ---------------------------------------------------------------------------
__global__ __launch_bounds__(256) void k_wconv(const float* __restrict__ W,
                                               unsigned short* __restrict__ Wb) {
    int i = blockIdx.x * 256 + threadIdx.x;
    Wb[i] = f2bf(W[i]);
}

// ---------------------------------------------------------------------------
// K1: argmin_n d2(s,n).  Reference fp32 op order: ((s2 - 2*dot) + p2).
// ---------------------------------------------------------------------------
__global__ __launch_bounds__(256) void k_argmin(const float* __restrict__ seed,
                                                const float* __restrict__ pl,
                                                int* __restrict__ idx_out) {
    const int t    = threadIdx.x;
    const int lane = t & 63;
    const int w    = t >> 6;
    const int gw   = blockIdx.x * 4 + w;
    const int b    = gw >> 8;
    const int s0   = (gw & 255) * 4;

    float sx[4], sy[4], sz[4], s2[4], best[4];
    int   bidx[4];
#pragma unroll
    for (int j = 0; j < 4; ++j) {
        const float* sp = seed + (size_t)(b * S_ + s0 + j) * 3;
        sx[j] = sp[0]; sy[j] = sp[1]; sz[j] = sp[2];
        s2[j] = __fadd_rn(__fadd_rn(__fmul_rn(sx[j], sx[j]),
                                    __fmul_rn(sy[j], sy[j])),
                          __fmul_rn(sz[j], sz[j]));
        best[j] = 3.4e38f;
        bidx[j] = 0;
    }
    const float* pb = pl + (size_t)b * N_ * 3;

    for (int k = 0; k < N_ / 64; ++k) {
        const int   n  = k * 64 + lane;
        const float px = pb[n * 3 + 0];
        const float py = pb[n * 3 + 1];
        const float pz = pb[n * 3 + 2];
        const float p2 = __fadd_rn(__fadd_rn(__fmul_rn(px, px),
                                             __fmul_rn(py, py)),
                                   __fmul_rn(pz, pz));
#pragma unroll
        for (int j = 0; j < 4; ++j) {
            float dot = __fadd_rn(__fadd_rn(__fmul_rn(sx[j], px),
                                            __fmul_rn(sy[j], py)),
                                  __fmul_rn(sz[j], pz));
            float d2  = __fadd_rn(__fsub_rn(s2[j], __fmul_rn(2.0f, dot)), p2);
            if (d2 < best[j]) { best[j] = d2; bidx[j] = n; }
        }
    }

#pragma unroll
    for (int j = 0; j < 4; ++j) {
#pragma unroll
        for (int off = 32; off >= 1; off >>= 1) {
            float ob = __shfl_xor(best[j], off, 64);
            int   oi = __shfl_xor(bidx[j], off, 64);
            bool take = (ob < best[j]) || (ob == best[j] && oi < bidx[j]);
            if (take) { best[j] = ob; bidx[j] = oi; }
        }
        if (lane == 0) idx_out[b * S_ + s0 + j] = bidx[j];
    }
}

// ---------------------------------------------------------------------------
// K2 (ROUND 4): P[b][n][o] = bf16( sum_c f[b][c][n] * Wb[o][c] )  for ALL n.
// n-block 128, o-block 256 (full OUT -> f read exactly once), BK=32.
// f-tile: coalesced f32x4 along n; each thread owns a 4c x 4n block ->
// in-REGISTER transpose (no shuffles), 4x b64 writes to ldsF[n][k] (rowB=36).
// W-tile via global_load_lds. MFMA: A=f-frag (rows n), B=W-frag (rows o).
// ---------------------------------------------------------------------------
__global__ __launch_bounds__(256, 2) void k_pgemm(const float* __restrict__ f,
                                                  const unsigned short* __restrict__ Wb,
                                                  unsigned short* __restrict__ P) {
    __shared__ unsigned short ldsF[128 * 36];   // [n][k], 9216 shorts = 18 KB
    __shared__ unsigned short ldsW[256 * 32];   // [o][k], 16 KB
    const int t    = threadIdx.x;
    const int b    = blockIdx.x >> 5;
    const int nt   = blockIdx.x & 31;
    const int n0   = nt * 128;
    const int lane = t & 63;
    const int w    = t >> 6;
    const int wm   = w & 1;           // n-half (0..1) -> 64 rows
    const int wo   = w >> 1;          // o-half (0..1) -> 128 cols
    const int quad = lane >> 4, l16 = lane & 15;

    f32x4 acc[4][8];
#pragma unroll
    for (int i = 0; i < 4; ++i)
#pragma unroll
        for (int j = 0; j < 8; ++j) acc[i][j] = (f32x4){0.f, 0.f, 0.f, 0.f};

    const int cb = t >> 5;            // 0..7  (4-c block)
    const int nb = t & 31;            // 0..31 (4-n block)
    const float* fB = f + (size_t)b * C_ * N_ + n0 + nb * 4;
    const unsigned short* wSrc = Wb + (size_t)(t >> 2) * C_ + (t & 3) * 8;

    for (int kt = 0; kt < C_ / 32; ++kt) {
        const int k0 = kt * 32;
        // stage W: 256 rows x 32 k, 4 DMA issues (dst = uniform + lane*16B)
#pragma unroll
        for (int i = 0; i < 4; ++i)
            gl_lds16(wSrc + (size_t)i * 64 * C_ + k0, ldsW + i * 2048 + t * 8);
        // stage f-tile 32c x 128n with in-register 4x4 transpose
        f32x4 v[4];
#pragma unroll
        for (int j = 0; j < 4; ++j)
            v[j] = *(const f32x4*)(fB + (size_t)(k0 + cb * 4 + j) * N_);
#pragma unroll
        for (int i = 0; i < 4; ++i) {
            bf16x4 pk = {(short)f2bf(v[0][i]), (short)f2bf(v[1][i]),
                         (short)f2bf(v[2][i]), (short)f2bf(v[3][i])};
            *(bf16x4*)(ldsF + (nb * 4 + i) * 36 + cb * 4) = pk;
        }
        __syncthreads();

        bf16x8 aF[4], bF[8];
#pragma unroll
        for (int mi = 0; mi < 4; ++mi) {
            const unsigned short* p = ldsF + (wm * 64 + mi * 16 + l16) * 36 + quad * 8;
            bf16x4 lo = *(const bf16x4*)p;
            bf16x4 hi = *(const bf16x4*)(p + 4);
            aF[mi] = __builtin_shufflevector(lo, hi, 0, 1, 2, 3, 4, 5, 6, 7);
        }
#pragma unroll
        for (int oi = 0; oi < 8; ++oi)
            bF[oi] = *(const bf16x8*)(ldsW + (wo * 128 + oi * 16 + l16) * 32 + quad * 8);
#pragma unroll
        for (int mi = 0; mi < 4; ++mi)
#pragma unroll
            for (int oi = 0; oi < 8; ++oi)
                acc[mi][oi] = __builtin_amdgcn_mfma_f32_16x16x32_bf16(
                    aF[mi], bF[oi], acc[mi][oi], 0, 0, 0);
        __syncthreads();
    }

    // epilogue: D row = n (A side), col = o (B side); store bf16
    unsigned short* Pb = P + ((size_t)b * N_ + n0) * OUT_;
#pragma unroll
    for (int mi = 0; mi < 4; ++mi) {
#pragma unroll
        for (int r = 0; r < 4; ++r) {
            const int n = wm * 64 + mi * 16 + quad * 4 + r;
            unsigned short* row = Pb + (size_t)n * OUT_;
#pragma unroll
            for (int oi = 0; oi < 8; ++oi) {
                const int o = wo * 128 + oi * 16 + l16;
                row[o] = f2bf(acc[mi][oi][r]);
            }
        }
    }
}

// ---------------------------------------------------------------------------
// K3 (ROUND 4): out[b][o][s] = f32(P[b][idx[b][s]][o]) + bias[o]
// Coalesced 512B row-gather -> LDS [s][o] (rowB=260 shorts: 4-way reads) ->
// transposed store, s-contiguous 256B per instr. grid 16 x 16 (s-tile 64).
// ---------------------------------------------------------------------------
__global__ __launch_bounds__(256) void k_out(const unsigned short* __restrict__ P,
                                             const int* __restrict__ idx,
                                             const float* __restrict__ bias,
                                             float* __restrict__ out) {
    __shared__ unsigned short tl[64 * 260];
    const int t  = threadIdx.x;
    const int b  = blockIdx.x >> 4;
    const int st = blockIdx.x & 15;
    const int s0 = st * 64;
    const unsigned short* Pb = P + (size_t)b * N_ * OUT_;

#pragma unroll
    for (int i = 0; i < 8; ++i) {
        const int g = i * 256 + t;
        const int s = g >> 5;            // 0..63
        const int p = g & 31;            // 16B chunk within 512B row
        const int n = idx[b * S_ + s0 + s];
        const unsigned short* src = Pb + (size_t)n * OUT_ + p * 8;
        uint2 u0 = *(const uint2*)src;
        uint2 u1 = *(const uint2*)(src + 4);
        *(uint2*)(tl + s * 260 + p * 8)     = u0;   // b64 writes (8B aligned)
        *(uint2*)(tl + s * 260 + p * 8 + 4) = u1;
    }
    __syncthreads();

    const int lane = t & 63;
    const int w    = t >> 6;
    float* ob = out + (size_t)b * OUT_ * S_ + s0;
#pragma unroll 4
    for (int oo = 0; oo < 64; ++oo) {
        const int o = w * 64 + oo;
        const unsigned short u = tl[lane * 260 + o];
        const float val = __uint_as_float(((unsigned int)u) << 16) + bias[o];
        ob[(size_t)o * S_ + lane] = val;
    }
}

// ---------------------------------------------------------------------------
// Workspace: [0,64K) idx int32[16][1024]
//            [64K,64K+384K) Wb bf16[256][768]
//            [512K, 512K+33.6MB) P bf16[16][4096][256]
// ---------------------------------------------------------------------------
extern "C" void kernel_launch(void* const* d_in, const int* in_sizes, int n_in,
                              void* d_out, int out_size, void* d_ws, size_t ws_size,
                              hipStream_t stream) {
    const float* seed = (const float*)d_in[0];   // [16,1024,3]
    const float* pl   = (const float*)d_in[1];   // [16,4096,3]
    const float* f    = (const float*)d_in[2];   // [16,768,4096]
    const float* W    = (const float*)d_in[3];   // [256,768]
    const float* bias = (const float*)d_in[4];   // [256]
    float* out = (float*)d_out;                  // [16,256,1024] fp32

    int* idx            = (int*)d_ws;
    unsigned short* Wb  = (unsigned short*)((char*)d_ws + 65536);
    unsigned short* P   = (unsigned short*)((char*)d_ws + 524288);

    k_wconv <<<768,  256, 0, stream>>>(W, Wb);
    k_argmin<<<1024, 256, 0, stream>>>(seed, pl, idx);
    k_pgemm <<<512,  256, 0, stream>>>(f, Wb, P);
    k_out   <<<256,  256, 0, stream>>>(P, idx, bias, out);
}